// Round 2
// baseline (1342.671 us; speedup 1.0000x reference)
//
#include <hip/hip_runtime.h>
#include <hip/hip_bf16.h>

#define MM 32
#define KK 8192
#define NN 28672
#define NB_COUNT (NN / 64)          /* 448 n-regions of 64 cols */
#define REGION_BYTES (2048 * 64)    /* 128 KiB: one (nb,kc) weight region */

typedef _Float16 half8   __attribute__((ext_vector_type(8)));
typedef __fp16   fp16x2  __attribute__((ext_vector_type(2)));
typedef float    floatx4 __attribute__((ext_vector_type(4)));
typedef int      intx4   __attribute__((ext_vector_type(4)));
typedef unsigned int uintx2 __attribute__((ext_vector_type(2)));

// ---------------- act fp32 -> fp16 pre-convert (exact: data originated fp16)
__global__ __launch_bounds__(256) void act_cvt_kernel(
    const float* __restrict__ act, __fp16* __restrict__ act16)
{
    int i = (blockIdx.x * 256 + threadIdx.x) * 4;   // MM*KK = 262144 = 256*256*4
    floatx4 v = *(const floatx4*)(act + i);
    fp16x2 lo = __builtin_amdgcn_cvt_pkrtz(v[0], v[1]);
    fp16x2 hi = __builtin_amdgcn_cvt_pkrtz(v[2], v[3]);
    __fp16* o = act16 + i;
    *(fp16x2*)(o)     = lo;
    *(fp16x2*)(o + 2) = hi;
}

// ---------------- pass 1: repack weight int32 [K][N] -> int8 in GEMM order.
// Canonical address for element (k,n), matching gemm_pack_kernel's reads:
//   kc=k>>11, s=(k&2047)>>5, quad=(k&31)>>3, j=k&7
//   nb=n>>6,  wave=(n&63)>>4, col=n&15
//   addr = ((kc*448+nb)<<17) + (s<<11) + (wave<<9) + (quad<<7) + (col<<3) + j
// Block = 32 k-rows x 512 n-cols. Reads: per row 2 KB contiguous (page-friendly).
// Writes: each thread emits one full 64-B line (4x dwordx4); per block the
// writes form 8 contiguous 2-KB chunks. Both DRAM streams are sequential.
__global__ __launch_bounds__(256) void repack_kernel(
    const int* __restrict__ weight, unsigned char* __restrict__ wpack)
{
    const int t    = threadIdx.x;
    const int slot = t & 63;                 // n8 slot within 512-col block
    const int kg   = t >> 6;                 // k-group 0..3 (8 rows each)
    const int n_base = blockIdx.x * 512 + slot * 8;
    const int k_base = blockIdx.y * 32 + kg * 8;

    const int* rp = weight + (size_t)k_base * NN + n_base;
    intx4 A[8], B[8];                        // A: cols 0..3, B: cols 4..7
#pragma unroll
    for (int j = 0; j < 8; ++j) {
        A[j] = *(const intx4*)(rp + (size_t)j * NN);
        B[j] = *(const intx4*)(rp + (size_t)j * NN + 4);
    }

    const int kc = k_base >> 11;
    const int s  = (k_base & 2047) >> 5;
    const int nb = n_base >> 6;
    const int wv = (n_base & 63) >> 4;       // n_base 8-aligned: all 8 cols same wave
    const int c0 = n_base & 15;              // 0 or 8
    unsigned char* op = wpack
        + (((size_t)kc * NB_COUNT + nb) << 17)
        + (s << 11) + (wv << 9) + (kg << 7) + (c0 << 3);

    // byte (i*8 + j) of the 64-B line = W[k_base+j][n_base+i] as int8
    int d[16];
#pragma unroll
    for (int i = 0; i < 4; ++i) {
        d[2 * i]      = (A[0][i] & 255) | ((A[1][i] & 255) << 8) |
                        ((A[2][i] & 255) << 16) | (A[3][i] << 24);
        d[2 * i + 1]  = (A[4][i] & 255) | ((A[5][i] & 255) << 8) |
                        ((A[6][i] & 255) << 16) | (A[7][i] << 24);
        d[2 * i + 8]  = (B[0][i] & 255) | ((B[1][i] & 255) << 8) |
                        ((B[2][i] & 255) << 16) | (B[3][i] << 24);
        d[2 * i + 9]  = (B[4][i] & 255) | ((B[5][i] & 255) << 8) |
                        ((B[6][i] & 255) << 16) | (B[7][i] << 24);
    }
#pragma unroll
    for (int q = 0; q < 4; ++q) {
        intx4 v = {d[4 * q], d[4 * q + 1], d[4 * q + 2], d[4 * q + 3]};
        *(intx4*)(op + q * 16) = v;
    }
}

// ---------------- pass 2: GEMM over packed int8 weight. Each block's weight
// is one contiguous 128-KB region; per k-step each lane loads ONE dwordx2
// (512 B contiguous per wave instr), unpacks 8 int8 -> fp16 in registers,
// 2 MFMA. Double-buffered with named buffers (compile-time indexing only).
// Fragment mapping identical to the verified round-0/1 kernels.
template <int KSPLIT>
__global__ __launch_bounds__(256) void gemm_pack_kernel(
    const __fp16*        __restrict__ act16,
    const unsigned char* __restrict__ wpack,
    float*               __restrict__ ws)
{
    const int lane = threadIdx.x & 63;
    const int wave = threadIdx.x >> 6;
    const int col  = lane & 15;
    const int quad = lane >> 4;

    const int nb  = blockIdx.x;
    const int kcb = blockIdx.y;
    const int kc  = kcb * (KK / KSPLIT);
    constexpr int NSTEP = (KK / KSPLIT) / 32;   // 64 K-steps of 32

    const unsigned char* wp = wpack
        + (((size_t)kcb * NB_COUNT + nb) << 17)
        + (wave << 9) + (lane << 3);
    const __fp16* ap0 = act16 + (size_t)col * KK + kc + quad * 8;
    const __fp16* ap1 = ap0 + (size_t)16 * KK;

    floatx4 acc0 = {0.f, 0.f, 0.f, 0.f};   // m = 0..15
    floatx4 acc1 = {0.f, 0.f, 0.f, 0.f};   // m = 16..31

    uintx2 wA, wB;
    half8  aA0, aA1, aB0, aB1;

    auto load_step = [&](int s, uintx2& w, half8& a0, half8& a1) {
        w  = *(const uintx2*)(wp + (size_t)s * 2048);
        a0 = *(const half8*)(ap0 + s * 32);
        a1 = *(const half8*)(ap1 + s * 32);
    };

    auto compute_step = [&](uintx2 w, const half8 a0, const half8 a1) {
        const unsigned lo = w[0], hi = w[1];
        int j0 = (int)(lo << 24) >> 24;
        int j1 = (int)(lo << 16) >> 24;
        int j2 = (int)(lo <<  8) >> 24;
        int j3 = (int)lo >> 24;
        int j4 = (int)(hi << 24) >> 24;
        int j5 = (int)(hi << 16) >> 24;
        int j6 = (int)(hi <<  8) >> 24;
        int j7 = (int)hi >> 24;
        fp16x2 p0 = __builtin_amdgcn_cvt_pkrtz((float)j0, (float)j1);
        fp16x2 p1 = __builtin_amdgcn_cvt_pkrtz((float)j2, (float)j3);
        fp16x2 p2 = __builtin_amdgcn_cvt_pkrtz((float)j4, (float)j5);
        fp16x2 p3 = __builtin_amdgcn_cvt_pkrtz((float)j6, (float)j7);
        half8 b;
        b[0] = p0[0]; b[1] = p0[1]; b[2] = p1[0]; b[3] = p1[1];
        b[4] = p2[0]; b[5] = p2[1]; b[6] = p3[0]; b[7] = p3[1];
        acc0 = __builtin_amdgcn_mfma_f32_16x16x32_f16(a0, b, acc0, 0, 0, 0);
        acc1 = __builtin_amdgcn_mfma_f32_16x16x32_f16(a1, b, acc1, 0, 0, 0);
    };

    load_step(0, wA, aA0, aA1);
#pragma unroll 1
    for (int s = 0; s < NSTEP / 2 - 1; ++s) {
        load_step(2 * s + 1, wB, aB0, aB1);
        compute_step(wA, aA0, aA1);
        load_step(2 * s + 2, wA, aA0, aA1);
        compute_step(wB, aB0, aB1);
    }
    load_step(NSTEP - 1, wB, aB0, aB1);
    compute_step(wA, aA0, aA1);
    compute_step(wB, aB0, aB1);

    // partials: C/D layout col = lane&15, row = quad*4 + r
    float* wsb = ws + (size_t)kcb * MM * NN + nb * 64 + wave * 16 + col;
#pragma unroll
    for (int r = 0; r < 4; ++r) {
        int m0 = quad * 4 + r;
        wsb[(size_t)m0 * NN]        = acc0[r];
        wsb[(size_t)(m0 + 16) * NN] = acc1[r];
    }
}

// ---------------- reduce KSPLIT partials, apply scale
template <int KSPLIT>
__global__ __launch_bounds__(256) void finalize_kernel(
    const float* __restrict__ ws,
    const float* __restrict__ scale,
    float*       __restrict__ out)
{
    const int n = blockIdx.x * 256 + threadIdx.x;   // NN = 112*256
    const int m = blockIdx.y;
    float sum = 0.f;
#pragma unroll
    for (int c = 0; c < KSPLIT; ++c)
        sum += ws[(size_t)c * MM * NN + (size_t)m * NN + n];
    out[(size_t)m * NN + n] = sum * scale[n];
}

// ---------------- fallback (ws too small): direct kernel, fused epilogue
__global__ __launch_bounds__(256) void gemm_direct_kernel(
    const float* __restrict__ act,
    const int*   __restrict__ weight,
    const float* __restrict__ scale,
    float*       __restrict__ out)
{
    const int lane = threadIdx.x & 63;
    const int wave = threadIdx.x >> 6;
    const int col  = lane & 15;
    const int quad = lane >> 4;
    const int n0 = blockIdx.x * 64 + wave * 16 + col;

    floatx4 acc0 = {0.f, 0.f, 0.f, 0.f};
    floatx4 acc1 = {0.f, 0.f, 0.f, 0.f};
    const float* ap0 = act + (size_t)col * KK + quad * 8;
    const float* ap1 = ap0 + (size_t)16 * KK;
    const int* wp = weight + (size_t)(quad * 8) * NN + n0;

    for (int s = 0; s < KK / 32; ++s) {
        floatx4 a0lo = *(const floatx4*)(ap0);
        floatx4 a0hi = *(const floatx4*)(ap0 + 4);
        floatx4 a1lo = *(const floatx4*)(ap1);
        floatx4 a1hi = *(const floatx4*)(ap1 + 4);
        half8 a0, a1, b;
#pragma unroll
        for (int j = 0; j < 4; ++j) {
            a0[j] = (_Float16)a0lo[j]; a0[j + 4] = (_Float16)a0hi[j];
            a1[j] = (_Float16)a1lo[j]; a1[j + 4] = (_Float16)a1hi[j];
        }
#pragma unroll
        for (int j = 0; j < 8; ++j)
            b[j] = (_Float16)wp[(size_t)j * NN];
        acc0 = __builtin_amdgcn_mfma_f32_16x16x32_f16(a0, b, acc0, 0, 0, 0);
        acc1 = __builtin_amdgcn_mfma_f32_16x16x32_f16(a1, b, acc1, 0, 0, 0);
        ap0 += 32; ap1 += 32; wp += (size_t)32 * NN;
    }
    float sc = scale[n0];
#pragma unroll
    for (int r = 0; r < 4; ++r) {
        int m0 = quad * 4 + r;
        out[(size_t)m0 * NN + n0]        = acc0[r] * sc;
        out[(size_t)(m0 + 16) * NN + n0] = acc1[r] * sc;
    }
}

extern "C" void kernel_launch(void* const* d_in, const int* in_sizes, int n_in,
                              void* d_out, int out_size, void* d_ws, size_t ws_size,
                              hipStream_t stream)
{
    const float* act    = (const float*)d_in[0];
    const int*   weight = (const int*)d_in[1];
    const float* scale  = (const float*)d_in[2];
    float*       out    = (float*)d_out;

    constexpr int KSPLIT = 4;
    const size_t partials_bytes = (size_t)KSPLIT * MM * NN * sizeof(float); // 14,680,064
    const size_t act16_off      = partials_bytes;
    const size_t wpack_off      = act16_off + (size_t)MM * KK * sizeof(__fp16); // 15,204,352
    const size_t need           = wpack_off + (size_t)KK * NN;                   // ~239 MB

    if (ws_size >= need) {
        float*         ws_part = (float*)d_ws;
        __fp16*        act16   = (__fp16*)((char*)d_ws + act16_off);
        unsigned char* wpack   = (unsigned char*)d_ws + wpack_off;

        act_cvt_kernel<<<MM * KK / (256 * 4), 256, 0, stream>>>(act, act16);

        dim3 rgrid(NN / 512, KK / 32);   // 56 x 256
        repack_kernel<<<rgrid, 256, 0, stream>>>(weight, wpack);

        dim3 ggrid(NB_COUNT, KSPLIT);    // 448 x 4
        gemm_pack_kernel<KSPLIT><<<ggrid, 256, 0, stream>>>(act16, wpack, ws_part);

        dim3 fgrid(NN / 256, MM);
        finalize_kernel<KSPLIT><<<fgrid, 256, 0, stream>>>(ws_part, scale, out);
    } else {
        gemm_direct_kernel<<<NN / 64, 256, 0, stream>>>(act, weight, scale, out);
    }
}

// Round 4
// 1327.772 us; speedup vs baseline: 1.0112x; 1.0112x over previous
//
#include <hip/hip_runtime.h>
#include <hip/hip_bf16.h>

#define MM 32
#define KK 8192
#define NN 28672
#define NB_COUNT (NN / 64)          /* 448 n-regions of 64 cols */

typedef _Float16 half8   __attribute__((ext_vector_type(8)));
typedef __fp16   fp16x2  __attribute__((ext_vector_type(2)));
typedef float    floatx4 __attribute__((ext_vector_type(4)));
typedef int      intx4   __attribute__((ext_vector_type(4)));

// ---------------- act fp32 -> fp16 pre-convert (exact: data originated fp16)
__global__ __launch_bounds__(256) void act_cvt_kernel(
    const float* __restrict__ act, __fp16* __restrict__ act16)
{
    int i = (blockIdx.x * 256 + threadIdx.x) * 4;   // MM*KK = 262144 = 256*256*4
    floatx4 v = *(const floatx4*)(act + i);
    fp16x2 lo = __builtin_amdgcn_cvt_pkrtz(v[0], v[1]);
    fp16x2 hi = __builtin_amdgcn_cvt_pkrtz(v[2], v[3]);
    __fp16* o = act16 + i;
    *(fp16x2*)(o)     = lo;
    *(fp16x2*)(o + 2) = hi;
}

// ---------------- packed-weight address map (int8), element (k, n):
//   kcb = k>>11 (KSPLIT=4), nb = n>>6  -> region (kcb*448+nb), 128 KiB each
//   within region:
//     ssl  = (k>>6)&31  -> <<12   (one 4-KiB ss-step: 64 k x 64 n)
//     quad = (k>>3)&3   -> <<10
//     wn   = (n>>4)&3   -> <<8
//     col  = n&15       -> <<4
//     hs   = (k>>5)&1   -> <<3
//     j    = k&7        -> <<0
// GEMM lane (quad,col) of wave wn reads 16 B at quad<<10|wn<<8|col<<4, step
// stride 4 KiB -> each quad-stream walks its region sequentially.
// Repack block (fixed ssl,quad) writes 1-KiB contiguous runs per region.

// ---------------- pass 1: repack. 512 blocks; block = 16 rows
// { k0..k0+7 (hs=0), k0+32..k0+39 (hs=1) } x FULL 28672-col width, where
// k0 = ss*64 + q*8, ss = blockIdx.x>>2, q = blockIdx.x&3.
// Reads: per wave instr 1 KiB dense; each of the 16 row-streams is a 114-KiB
// sequential stream (long-run, page-friendly). Each lane assembles 4 complete
// 16-B k-major units in registers (shift/mask; exact for int8 in int32) and
// writes 64 B contiguous.
__global__ __launch_bounds__(256) void repack_kernel(
    const int* __restrict__ weight, unsigned char* __restrict__ wpack)
{
    const int t   = threadIdx.x;
    const int ss  = blockIdx.x >> 2;     // 0..127
    const int q   = blockIdx.x & 3;
    const int kcb = ss >> 5;
    const int ssl = ss & 31;
    const int k0  = ss * 64 + q * 8;     // hs=0 rows; hs=1 rows at +32

    const int* r0 = weight + (size_t)k0 * NN;
    const int* r1 = r0 + (size_t)32 * NN;

    for (int i = 0; i < 28; ++i) {
        const int idx  = i * 256 + t;          // intx4 index, 0..7167
        const int nofs = idx * 4;              // starting n (int units)

        intx4 a[8], b[8];
#pragma unroll
        for (int j = 0; j < 8; ++j) {
            a[j] = *(const intx4*)(r0 + (size_t)j * NN + nofs);
            b[j] = *(const intx4*)(r1 + (size_t)j * NN + nofs);
        }

        const int nb   = nofs >> 6;
        const int wn   = (nofs >> 4) & 3;
        const int col0 = nofs & 15;            // 0,4,8,12
        unsigned char* up = wpack
            + (((size_t)kcb * NB_COUNT + nb) << 17)
            + (ssl << 12) + (q << 10) + (wn << 8) + (col0 << 4);

#pragma unroll
        for (int ii = 0; ii < 4; ++ii) {
            // unit bytes 0..7  = W[k0+j][n] (hs=0), 8..15 = W[k0+32+j][n]
            int d0 = (a[0][ii] & 255) | ((a[1][ii] & 255) << 8) |
                     ((a[2][ii] & 255) << 16) | (a[3][ii] << 24);
            int d1 = (a[4][ii] & 255) | ((a[5][ii] & 255) << 8) |
                     ((a[6][ii] & 255) << 16) | (a[7][ii] << 24);
            int d2 = (b[0][ii] & 255) | ((b[1][ii] & 255) << 8) |
                     ((b[2][ii] & 255) << 16) | (b[3][ii] << 24);
            int d3 = (b[4][ii] & 255) | ((b[5][ii] & 255) << 8) |
                     ((b[6][ii] & 255) << 16) | (b[7][ii] << 24);
            intx4 u = {d0, d1, d2, d3};
            *(intx4*)(up + 16 * ii) = u;
        }
    }
}

// ---------------- pass 2: GEMM over packed int8 weight. Block owns one
// contiguous 128-KiB region; per ss-step each lane loads ONE dwordx4 whose
// 16 bytes are the B-fragments for TWO k-steps (hs=0, hs=1). Four quad
// streams per block, each sequential. Double-buffered with named buffers
// (all indexing compile-time). Fragment roles identical to verified rounds.
template <int KSPLIT>
__global__ __launch_bounds__(256) void gemm_pack_kernel(
    const __fp16*        __restrict__ act16,
    const unsigned char* __restrict__ wpack,
    float*               __restrict__ ws)
{
    const int lane = threadIdx.x & 63;
    const int wave = threadIdx.x >> 6;
    const int col  = lane & 15;
    const int quad = lane >> 4;

    const int nb  = blockIdx.x;
    const int kcb = blockIdx.y;
    const int kc  = kcb * (KK / KSPLIT);        // k-chunk base (2048)
    constexpr int NSS = (KK / KSPLIT) / 64;     // 32 ss-steps

    const unsigned char* wp = wpack
        + (((size_t)kcb * NB_COUNT + nb) << 17)
        + (quad << 10) + (wave << 8) + (col << 4);
    const __fp16* ap0 = act16 + (size_t)col * KK + kc + quad * 8;
    const __fp16* ap1 = ap0 + (size_t)16 * KK;

    floatx4 acc0 = {0.f, 0.f, 0.f, 0.f};   // m = 0..15
    floatx4 acc1 = {0.f, 0.f, 0.f, 0.f};   // m = 16..31

    intx4 wA, wB;
    half8 aA00, aA01, aA10, aA11, aB00, aB01, aB10, aB11;

    auto load_step = [&](int s, intx4& wq, half8& a00, half8& a01,
                         half8& a10, half8& a11) {
        wq  = *(const intx4*)(wp + ((size_t)s << 12));
        a00 = *(const half8*)(ap0 + s * 64);
        a01 = *(const half8*)(ap0 + s * 64 + 32);
        a10 = *(const half8*)(ap1 + s * 64);
        a11 = *(const half8*)(ap1 + s * 64 + 32);
    };

    auto bfrag = [](unsigned lo, unsigned hi) -> half8 {
        int j0 = (int)(lo << 24) >> 24;
        int j1 = (int)(lo << 16) >> 24;
        int j2 = (int)(lo <<  8) >> 24;
        int j3 = (int)lo >> 24;
        int j4 = (int)(hi << 24) >> 24;
        int j5 = (int)(hi << 16) >> 24;
        int j6 = (int)(hi <<  8) >> 24;
        int j7 = (int)hi >> 24;
        fp16x2 p0 = __builtin_amdgcn_cvt_pkrtz((float)j0, (float)j1);
        fp16x2 p1 = __builtin_amdgcn_cvt_pkrtz((float)j2, (float)j3);
        fp16x2 p2 = __builtin_amdgcn_cvt_pkrtz((float)j4, (float)j5);
        fp16x2 p3 = __builtin_amdgcn_cvt_pkrtz((float)j6, (float)j7);
        half8 b;
        b[0] = p0[0]; b[1] = p0[1]; b[2] = p1[0]; b[3] = p1[1];
        b[4] = p2[0]; b[5] = p2[1]; b[6] = p3[0]; b[7] = p3[1];
        return b;
    };

    auto compute_step = [&](const intx4 wq, const half8 a00, const half8 a01,
                            const half8 a10, const half8 a11) {
        half8 bh0 = bfrag((unsigned)wq[0], (unsigned)wq[1]);   // hs=0 k-step
        half8 bh1 = bfrag((unsigned)wq[2], (unsigned)wq[3]);   // hs=1 k-step
        acc0 = __builtin_amdgcn_mfma_f32_16x16x32_f16(a00, bh0, acc0, 0, 0, 0);
        acc1 = __builtin_amdgcn_mfma_f32_16x16x32_f16(a10, bh0, acc1, 0, 0, 0);
        acc0 = __builtin_amdgcn_mfma_f32_16x16x32_f16(a01, bh1, acc0, 0, 0, 0);
        acc1 = __builtin_amdgcn_mfma_f32_16x16x32_f16(a11, bh1, acc1, 0, 0, 0);
    };

    load_step(0, wA, aA00, aA01, aA10, aA11);
#pragma unroll 1
    for (int s = 0; s < NSS / 2 - 1; ++s) {
        load_step(2 * s + 1, wB, aB00, aB01, aB10, aB11);
        compute_step(wA, aA00, aA01, aA10, aA11);
        load_step(2 * s + 2, wA, aA00, aA01, aA10, aA11);
        compute_step(wB, aB00, aB01, aB10, aB11);
    }
    load_step(NSS - 1, wB, aB00, aB01, aB10, aB11);
    compute_step(wA, aA00, aA01, aA10, aA11);
    compute_step(wB, aB00, aB01, aB10, aB11);

    // partials: C/D layout col = lane&15, row = quad*4 + r
    float* wsb = ws + (size_t)kcb * MM * NN + nb * 64 + wave * 16 + col;
#pragma unroll
    for (int r = 0; r < 4; ++r) {
        int m0 = quad * 4 + r;
        wsb[(size_t)m0 * NN]        = acc0[r];
        wsb[(size_t)(m0 + 16) * NN] = acc1[r];
    }
}

// ---------------- reduce KSPLIT partials, apply scale
template <int KSPLIT>
__global__ __launch_bounds__(256) void finalize_kernel(
    const float* __restrict__ ws,
    const float* __restrict__ scale,
    float*       __restrict__ out)
{
    const int n = blockIdx.x * 256 + threadIdx.x;   // NN = 112*256
    const int m = blockIdx.y;
    float sum = 0.f;
#pragma unroll
    for (int c = 0; c < KSPLIT; ++c)
        sum += ws[(size_t)c * MM * NN + (size_t)m * NN + n];
    out[(size_t)m * NN + n] = sum * scale[n];
}

// ---------------- fallback (ws too small): direct kernel, fused epilogue
__global__ __launch_bounds__(256) void gemm_direct_kernel(
    const float* __restrict__ act,
    const int*   __restrict__ weight,
    const float* __restrict__ scale,
    float*       __restrict__ out)
{
    const int lane = threadIdx.x & 63;
    const int wave = threadIdx.x >> 6;
    const int col  = lane & 15;
    const int quad = lane >> 4;
    const int n0 = blockIdx.x * 64 + wave * 16 + col;

    floatx4 acc0 = {0.f, 0.f, 0.f, 0.f};
    floatx4 acc1 = {0.f, 0.f, 0.f, 0.f};
    const float* ap0 = act + (size_t)col * KK + quad * 8;
    const float* ap1 = ap0 + (size_t)16 * KK;
    const int* wp = weight + (size_t)(quad * 8) * NN + n0;

    for (int s = 0; s < KK / 32; ++s) {
        floatx4 a0lo = *(const floatx4*)(ap0);
        floatx4 a0hi = *(const floatx4*)(ap0 + 4);
        floatx4 a1lo = *(const floatx4*)(ap1);
        floatx4 a1hi = *(const floatx4*)(ap1 + 4);
        half8 a0, a1, b;
#pragma unroll
        for (int j = 0; j < 4; ++j) {
            a0[j] = (_Float16)a0lo[j]; a0[j + 4] = (_Float16)a0hi[j];
            a1[j] = (_Float16)a1lo[j]; a1[j + 4] = (_Float16)a1hi[j];
        }
#pragma unroll
        for (int j = 0; j < 8; ++j)
            b[j] = (_Float16)wp[(size_t)j * NN];
        acc0 = __builtin_amdgcn_mfma_f32_16x16x32_f16(a0, b, acc0, 0, 0, 0);
        acc1 = __builtin_amdgcn_mfma_f32_16x16x32_f16(a1, b, acc1, 0, 0, 0);
        ap0 += 32; ap1 += 32; wp += (size_t)32 * NN;
    }
    float sc = scale[n0];
#pragma unroll
    for (int r = 0; r < 4; ++r) {
        int m0 = quad * 4 + r;
        out[(size_t)m0 * NN + n0]        = acc0[r] * sc;
        out[(size_t)(m0 + 16) * NN + n0] = acc1[r] * sc;
    }
}

extern "C" void kernel_launch(void* const* d_in, const int* in_sizes, int n_in,
                              void* d_out, int out_size, void* d_ws, size_t ws_size,
                              hipStream_t stream)
{
    const float* act    = (const float*)d_in[0];
    const int*   weight = (const int*)d_in[1];
    const float* scale  = (const float*)d_in[2];
    float*       out    = (float*)d_out;

    constexpr int KSPLIT = 4;
    const size_t partials_bytes = (size_t)KSPLIT * MM * NN * sizeof(float); // 14,680,064
    const size_t act16_off      = partials_bytes;
    const size_t wpack_off      = act16_off + (size_t)MM * KK * sizeof(__fp16); // 15,204,352
    const size_t need           = wpack_off + (size_t)KK * NN;                   // ~250 MB

    if (ws_size >= need) {
        float*         ws_part = (float*)d_ws;
        __fp16*        act16   = (__fp16*)((char*)d_ws + act16_off);
        unsigned char* wpack   = (unsigned char*)d_ws + wpack_off;

        act_cvt_kernel<<<MM * KK / (256 * 4), 256, 0, stream>>>(act, act16);

        repack_kernel<<<512, 256, 0, stream>>>(weight, wpack);

        dim3 ggrid(NB_COUNT, KSPLIT);     // 448 x 4
        gemm_pack_kernel<KSPLIT><<<ggrid, 256, 0, stream>>>(act16, wpack, ws_part);

        dim3 fgrid(NN / 256, MM);
        finalize_kernel<KSPLIT><<<fgrid, 256, 0, stream>>>(ws_part, scale, out);
    } else {
        gemm_direct_kernel<<<NN / 64, 256, 0, stream>>>(act, weight, scale, out);
    }
}